// Round 1
// baseline (410.365 us; speedup 1.0000x reference)
//
#include <hip/hip_runtime.h>
#include <cstdint>
#include <cstddef>

typedef __bf16 bf16x8 __attribute__((ext_vector_type(8)));
typedef float f32x4 __attribute__((ext_vector_type(4)));

#define SEQ   4096
#define HID   1280
#define NH    16
#define HD    80

__device__ __forceinline__ unsigned short f2bf(float f) {
  unsigned int u = __float_as_uint(f);
  unsigned int r = u + 0x7FFFu + ((u >> 16) & 1u);   // RNE
  return (unsigned short)(r >> 16);
}
__device__ __forceinline__ float bf2f(unsigned short h) {
  return __uint_as_float(((unsigned int)h) << 16);
}
__device__ __forceinline__ __bf16 us2bf(unsigned short u) {
  union { unsigned short s; __bf16 b; } c; c.s = u; return c.b;
}
__device__ __forceinline__ void dma16(const void* g, void* l) {
  __builtin_amdgcn_global_load_lds((const __attribute__((address_space(1))) unsigned int*)g,
                                   (__attribute__((address_space(3))) unsigned int*)l, 16, 0, 0);
}

// ---------------- split: f32 -> bf16 hi only ---------------------------------
__global__ __launch_bounds__(256) void split_hi_kernel(const float* __restrict__ x,
                                                       unsigned short* __restrict__ hi,
                                                       int n4) {
  int i = blockIdx.x * 256 + threadIdx.x;
  if (i >= n4) return;
  float4 v = *((const float4*)x + i);
  *((ushort4*)hi + i) = make_ushort4(f2bf(v.x), f2bf(v.y), f2bf(v.z), f2bf(v.w));
}

// ---------------- transpose + split weights (hi/lo) --------------------------
__global__ __launch_bounds__(256) void tsplit_kernel(const float* __restrict__ W,
                                                     unsigned short* __restrict__ Thi,
                                                     unsigned short* __restrict__ Tlo,
                                                     int K, int N) {
  __shared__ float tile[32][33];
  int n0 = blockIdx.x * 32, k0 = blockIdx.y * 32;
  int tx = threadIdx.x & 31, ty = threadIdx.x >> 5;
#pragma unroll
  for (int i = 0; i < 32; i += 8)
    tile[ty + i][tx] = W[(size_t)(k0 + ty + i) * N + n0 + tx];
  __syncthreads();
#pragma unroll
  for (int i = 0; i < 32; i += 8) {
    float v = tile[tx][ty + i];
    size_t idx = (size_t)(n0 + ty + i) * K + (size_t)(k0 + tx);
    unsigned short h = f2bf(v);
    Thi[idx] = h;
    Tlo[idx] = f2bf(v - bf2f(h));
  }
}

// ---------------- 128x128 DMA GEMM, 2-term (A bf16, B hi/lo) -----------------
__global__ __launch_bounds__(256, 3) void gemm128_x2(
    const unsigned short* __restrict__ A, const unsigned short* __restrict__ Bh,
    const unsigned short* __restrict__ Bl, const float* __restrict__ bias,
    float* __restrict__ out0, float* __restrict__ out1, float* __restrict__ out2,
    int M, int N, int K) {
  __shared__ __align__(16) unsigned short sALL[3 * 8192];  // [A | Bh | Bl]

  const int t = threadIdx.x;
  const int lane = t & 63, wave = t >> 6;
  const int c16 = lane & 15, quad = lane >> 4;
  const int bm = blockIdx.y * 128, bn = blockIdx.x * 128;
  const int wr = (wave >> 1) * 64, wc = (wave & 1) * 64;
  const int lrow = lane >> 3;
  const int lswz = (lane & 7) ^ lrow;

  f32x4 acc[4][4];
#pragma unroll
  for (int i = 0; i < 4; ++i)
#pragma unroll
    for (int j = 0; j < 4; ++j) acc[i][j] = (f32x4){0.f, 0.f, 0.f, 0.f};

  // 48 DMA units/iter, 12 per wave; unit ua: arr = ua>>4 (0=A,1=Bh,2=Bl)
  const unsigned short* gp[12];
#pragma unroll
  for (int i = 0; i < 12; ++i) {
    const int ua = wave * 12 + i;
    const int arr = ua >> 4, sub = ua & 15;
    const unsigned short* g = (arr == 0) ? A : (arr == 1) ? Bh : Bl;
    const int rowg = ((arr == 0) ? bm : bn) + sub * 8 + lrow;
    gp[i] = g + (size_t)rowg * K + lswz * 8;
  }

  for (int k0 = 0; k0 < K; k0 += 64) {
    __syncthreads();
#pragma unroll
    for (int i = 0; i < 12; ++i)
      dma16(gp[i] + k0, &sALL[(wave * 12 + i) * 512]);
    __syncthreads();
#pragma unroll
    for (int ks = 0; ks < 2; ++ks) {
      bf16x8 a[4], bh[4], bl[4];
#pragma unroll
      for (int mi = 0; mi < 4; ++mi) {
        const int row = wr + mi * 16 + c16;
        const int off = row * 64 + (((ks * 4 + quad) ^ (row & 7)) * 8);
        a[mi] = *(const bf16x8*)&sALL[off];
      }
#pragma unroll
      for (int ni = 0; ni < 4; ++ni) {
        const int row = wc + ni * 16 + c16;
        const int off = row * 64 + (((ks * 4 + quad) ^ (row & 7)) * 8);
        bh[ni] = *(const bf16x8*)&sALL[8192 + off];
        bl[ni] = *(const bf16x8*)&sALL[16384 + off];
      }
#pragma unroll
      for (int mi = 0; mi < 4; ++mi)
#pragma unroll
        for (int ni = 0; ni < 4; ++ni) {
          acc[mi][ni] = __builtin_amdgcn_mfma_f32_16x16x32_bf16(a[mi], bh[ni], acc[mi][ni], 0, 0, 0);
          acc[mi][ni] = __builtin_amdgcn_mfma_f32_16x16x32_bf16(a[mi], bl[ni], acc[mi][ni], 0, 0, 0);
        }
    }
  }
  // epilogue: C/D layout col=c16, row=quad*4+r
#pragma unroll
  for (int ni = 0; ni < 4; ++ni) {
    int colg = bn + wc + ni * 16 + c16;
    float bv = bias[colg];
    float* op;
    int c = colg;
    if (c < 1280) op = out0;
    else if (c < 2560) { op = out1; c -= 1280; }
    else { op = out2; c -= 2560; }
#pragma unroll
    for (int mi = 0; mi < 4; ++mi)
#pragma unroll
      for (int r = 0; r < 4; ++r) {
        int rowg = bm + wr + mi * 16 + quad * 4 + r;
        op[(size_t)rowg * 1280 + c] = acc[mi][ni][r] + bv;
      }
  }
}

// ---------------- RoPE on q (in place, f32) + k -> packed bf16 hi/lo ---------
__global__ __launch_bounds__(256) void rope_pack_kernel(
    float* __restrict__ qf, const float* __restrict__ kf,
    const float* __restrict__ cs, const float* __restrict__ sn,
    unsigned short* __restrict__ khi, unsigned short* __restrict__ klo) {
  const int h = blockIdx.y;
  const int s = blockIdx.x * 64 + (threadIdx.x >> 2);
  const int p = threadIdx.x & 3;
  float* qrow = qf + (size_t)s * HID + h * HD;
  const float* krow = kf + (size_t)s * HID + h * HD;
  const float* cr = cs + (size_t)s * HD;
  const float* sr = sn + (size_t)s * HD;
  unsigned short* kh = khi + ((size_t)h * SEQ + s) * HD;
  unsigned short* kl = klo + ((size_t)h * SEQ + s) * HD;
#pragma unroll
  for (int j = 0; j < 10; ++j) {
    int d = 10 * p + j;           // 0..39
    float c0 = cr[d], s0 = sr[d], c1 = cr[d + 40], s1 = sr[d + 40];
    float q0 = qrow[d], q1 = qrow[d + 40];
    qrow[d]      = q0 * c0 - q1 * s0;
    qrow[d + 40] = q1 * c1 + q0 * s1;
    float k0 = krow[d], k1 = krow[d + 40];
    float kn0 = k0 * c0 - k1 * s0;
    float kn1 = k1 * c1 + k0 * s1;
    unsigned short h0 = f2bf(kn0), h1 = f2bf(kn1);
    kh[d] = h0;      kl[d] = f2bf(kn0 - bf2f(h0));
    kh[d + 40] = h1; kl[d + 40] = f2bf(kn1 - bf2f(h1));
  }
}

// ---------------- pack V^T: f32 [s][1280] -> bf16 hi/lo [h][80][4096] --------
__global__ __launch_bounds__(256) void vt_pack_kernel(const float* __restrict__ vf,
                                                      unsigned short* __restrict__ vthi,
                                                      unsigned short* __restrict__ vtlo,
                                                      unsigned int* __restrict__ ctr) {
  if (blockIdx.x == 0 && blockIdx.y == 0 && threadIdx.x == 0) *ctr = 0u;
  __shared__ unsigned short sTh[80][72];
  __shared__ unsigned short sTl[80][72];
  const int h = blockIdx.y;
  const int s0 = blockIdx.x * 64;
  const int t = threadIdx.x;
  {
    int row = t >> 2, p = (t & 3) * 20;
    const float* src = vf + (size_t)(s0 + row) * HID + h * HD + p;
#pragma unroll
    for (int i = 0; i < 5; ++i) {
      float4 v = *(const float4*)(src + 4 * i);
      float vv[4] = {v.x, v.y, v.z, v.w};
#pragma unroll
      for (int j = 0; j < 4; ++j) {
        int d = p + 4 * i + j;
        unsigned short hu = f2bf(vv[j]);
        sTh[d][row] = hu;
        sTl[d][row] = f2bf(vv[j] - bf2f(hu));
      }
    }
  }
  __syncthreads();
  if (t < 160) {
    int d = t >> 1, half = (t & 1) * 32;
    size_t base = (size_t)(h * HD + d) * SEQ + s0 + half;
#pragma unroll
    for (int i = 0; i < 8; ++i) {
      *(ushort4*)&vthi[base + 4 * i] = *(ushort4*)&sTh[d][half + 4 * i];
      *(ushort4*)&vtlo[base + 4 * i] = *(ushort4*)&sTl[d][half + 4 * i];
    }
  }
}

// ---------------- attention ---------------------------------------------------
// 512 blocks, one unit each (u>>5 = head, u&31 = 128-row q-tile).
// Each wave owns TWO 16-row q-subtiles (rows +0 and +64) sharing the same
// K/V LDS reads. K/V double-buffered (80 KB LDS -> 2 blocks/CU); one barrier
// per 64-key chunk, so the chunk-(i+1) DMA hides under the FULL chunk-i compute.

#define SMAX(SC, MI, LI, PK, AR, KBLO, KBHI)                                   \
  do {                                                                         \
    float mx = -1e30f;                                                         \
    _Pragma("unroll") for (int nt = 0; nt < 4; ++nt)                           \
        _Pragma("unroll") for (int r = 0; r < 4; ++r) {                        \
      const int kg = ck + nt * 16 + quad * 4 + r;                              \
      const bool ok = (kg >= (KBLO)) && (kg < (KBHI));                         \
      float v = ok ? SC[nt][r] : -1e30f;                                       \
      SC[nt][r] = v;                                                           \
      mx = fmaxf(mx, v);                                                       \
    }                                                                          \
    mx = fmaxf(mx, __shfl_xor(mx, 16));                                        \
    mx = fmaxf(mx, __shfl_xor(mx, 32));                                        \
    const float mnew = fmaxf(MI, mx);                                          \
    const float alpha = __expf(MI - mnew);                                     \
    float ps = 0.f;                                                            \
    _Pragma("unroll") for (int nt = 0; nt < 4; ++nt)                           \
        _Pragma("unroll") for (int r = 0; r < 4; ++r) {                        \
      const float s = SC[nt][r];                                               \
      const float p = (s > -1e29f) ? __expf(s - mnew) : 0.f;                   \
      ps += p;                                                                 \
      const unsigned int pu = __float_as_uint(p);                              \
      const unsigned short ph_ = (unsigned short)(pu >> 16);                   \
      const unsigned short pl_ = f2bf(p - bf2f(ph_));                          \
      PK[nt][r] = (unsigned int)ph_ | ((unsigned int)pl_ << 16);               \
    }                                                                          \
    ps += __shfl_xor(ps, 16);                                                  \
    ps += __shfl_xor(ps, 32);                                                  \
    LI = LI * alpha + ps;                                                      \
    MI = mnew;                                                                 \
    _Pragma("unroll") for (int r = 0; r < 4; ++r)                              \
        AR[r] = __uint_as_float((unsigned)__builtin_amdgcn_ds_bpermute(        \
            (quad * 4 + r) << 2, __float_as_int(alpha)));                      \
  } while (0)

#define BUILD_P(PK, PHU, PLU)                                                  \
  do {                                                                         \
    unsigned int vj[8];                                                        \
    _Pragma("unroll") for (int j = 0; j < 8; ++j) {                            \
      const int addr = (j < 4) ? addrA : addrB;                                \
      const int r = j & 3;                                                     \
      const int v0 = __builtin_amdgcn_ds_bpermute(addr, (int)PK[2 * ks + 0][r]); \
      const int v1 = __builtin_amdgcn_ds_bpermute(addr, (int)PK[2 * ks + 1][r]); \
      vj[j] = (unsigned int)((quad & 2) ? v1 : v0);                            \
    }                                                                          \
    PHU.w[0] = __builtin_amdgcn_perm(vj[1], vj[0], 0x05040100u);               \
    PHU.w[1] = __builtin_amdgcn_perm(vj[3], vj[2], 0x05040100u);               \
    PHU.w[2] = __builtin_amdgcn_perm(vj[5], vj[4], 0x05040100u);               \
    PHU.w[3] = __builtin_amdgcn_perm(vj[7], vj[6], 0x05040100u);               \
    PLU.w[0] = __builtin_amdgcn_perm(vj[1], vj[0], 0x07060302u);               \
    PLU.w[1] = __builtin_amdgcn_perm(vj[3], vj[2], 0x07060302u);               \
    PLU.w[2] = __builtin_amdgcn_perm(vj[5], vj[4], 0x07060302u);               \
    PLU.w[3] = __builtin_amdgcn_perm(vj[7], vj[6], 0x07060302u);               \
  } while (0)

__global__ __launch_bounds__(256, 2) void attn_kernel(
    const float* __restrict__ qf, const unsigned short* __restrict__ khi,
    const unsigned short* __restrict__ klo, const unsigned short* __restrict__ vthi,
    const unsigned short* __restrict__ vtlo, const int* __restrict__ cu,
    unsigned short* __restrict__ ohi) {
  __shared__ __align__(16) unsigned short sKh[2][5120], sKl[2][5120];
  __shared__ __align__(16) unsigned short sVh[2][5120], sVl[2][5120];
  // total LDS = 4*2*5120*2 = 81920 B exactly -> 2 blocks/CU

  const int t = threadIdx.x;
  const int lane = t & 63, wave = t >> 6;
  const int c16 = lane & 15, quad = lane >> 4;
  const int lr8 = lane >> 3;
  const int vswz = (lane & 7) ^ lr8;
  const int addrA = ((((2 * quad) & 3) * 16) + c16) << 2;
  const int addrB = ((((2 * quad + 1) & 3) * 16) + c16) << 2;

  // XCD-aware unit swizzle: block b runs on XCD b%8; XCD x gets units
  // [x*64, x*64+64) = heads 2x..2x+1  (bijective for 512 = 8*64 blocks)
  const unsigned int u = (blockIdx.x & 7) * 64 + (blockIdx.x >> 3);
  const int h = (int)(u >> 5);
  const int r0 = (int)(u & 31u) * 128;

  int cu_r[9];
#pragma unroll
  for (int i = 0; i < 9; ++i) cu_r[i] = cu[i];

  const int q0 = r0 + wave * 16 + c16;       // subtile-0 query row of this lane
  const int q1 = q0 + 64;                    // subtile-1 query row
  int sq0 = 0, sq1 = 0, sg0 = 0, sg1 = 0;
#pragma unroll
  for (int i = 1; i < 8; ++i) {
    sq0 += (q0 >= cu_r[i]) ? 1 : 0;
    sq1 += (q1 >= cu_r[i]) ? 1 : 0;
    sg0 += (r0 >= cu_r[i]) ? 1 : 0;
    sg1 += (r0 + 127 >= cu_r[i]) ? 1 : 0;
  }
  const int kb_lo0 = cu_r[sq0], kb_hi0 = cu_r[sq0 + 1];
  const int kb_lo1 = cu_r[sq1], kb_hi1 = cu_r[sq1 + 1];
  const int ck0 = cu_r[sg0] & ~63;
  const int kend = cu_r[sg1 + 1];
  const int nchunk = (kend - ck0 + 63) >> 6;

  // Q fragments (B-operand layout), scale folded; both subtiles
  const float qsc = 0.11180339887498949f;
  bf16x8 qh0[3], ql0[3], qh1[3], ql1[3];
  {
    const float* qrowA = qf + (size_t)q0 * HID + h * HD;
    const float* qrowB = qf + (size_t)q1 * HID + h * HD;
#pragma unroll
    for (int ks = 0; ks < 3; ++ks) {
      const int d = ks * 32 + quad * 8;
      bf16x8 hA = {}, lA = {}, hB = {}, lB = {};
      if (d < 80) {
        float4 a0 = *(const float4*)(qrowA + d);
        float4 a1 = *(const float4*)(qrowA + d + 4);
        float4 b0 = *(const float4*)(qrowB + d);
        float4 b1 = *(const float4*)(qrowB + d + 4);
        float va[8] = {a0.x, a0.y, a0.z, a0.w, a1.x, a1.y, a1.z, a1.w};
        float vb[8] = {b0.x, b0.y, b0.z, b0.w, b1.x, b1.y, b1.z, b1.w};
#pragma unroll
        for (int j = 0; j < 8; ++j) {
          float v = va[j] * qsc;
          unsigned short hu = f2bf(v);
          hA[j] = us2bf(hu); lA[j] = us2bf(f2bf(v - bf2f(hu)));
          v = vb[j] * qsc;
          hu = f2bf(v);
          hB[j] = us2bf(hu); lB[j] = us2bf(f2bf(v - bf2f(hu)));
        }
      }
      qh0[ks] = hA; ql0[ks] = lA; qh1[ks] = hB; ql1[ks] = lB;
    }
  }

  f32x4 O0[5], O1[5];
#pragma unroll
  for (int dt = 0; dt < 5; ++dt) {
    O0[dt] = (f32x4){0.f, 0.f, 0.f, 0.f};
    O1[dt] = (f32x4){0.f, 0.f, 0.f, 0.f};
  }
  float m0 = -1e30f, l0v = 0.f, m1 = -1e30f, l1v = 0.f;

  // stage K+V of chunk `ck` into buffer `buf` (per-wave plane split as before)
  auto STAGE = [&](int buf, int ck) {
    const unsigned short* gk = (wave & 2) ? klo : khi;
    unsigned short* lk = ((wave & 2) ? sKl[buf] : sKh[buf]) + (wave & 1) * 2560;
    const size_t kb = ((size_t)h * SEQ + ck) * 80 + (size_t)(wave & 1) * 2560 + lane * 8;
#pragma unroll
    for (int i2 = 0; i2 < 5; ++i2) dma16(gk + kb + i2 * 512, lk + i2 * 512);
    const unsigned short* gv = (wave & 2) ? vtlo : vthi;
    unsigned short* lv = (wave & 2) ? sVl[buf] : sVh[buf];
    const int half5 = (wave & 1) * 5;
#pragma unroll
    for (int i2 = 0; i2 < 5; ++i2) {
      const int uu = half5 + i2;
      dma16(gv + (size_t)(h * HD + 8 * uu + lr8) * SEQ + ck + vswz * 8, lv + uu * 512);
    }
  };

  STAGE(0, ck0);
  int cur = 0;

  for (int ci = 0; ci < nchunk; ++ci) {
    const int ck = ck0 + ci * 64;
    __syncthreads();   // drains DMA of chunk ci; all waves done reading buf cur^1
    if (ci + 1 < nchunk) STAGE(cur ^ 1, ck + 64);   // hides under full chunk compute

    // ---- QK: S^T = K * Q^T for BOTH subtiles, K fragments read once ----
    f32x4 sc0[4], sc1[4];
#pragma unroll
    for (int nt = 0; nt < 4; ++nt) {
      sc0[nt] = (f32x4){0.f, 0.f, 0.f, 0.f};
      sc1[nt] = (f32x4){0.f, 0.f, 0.f, 0.f};
    }
    __builtin_amdgcn_s_setprio(1);
#pragma unroll
    for (int nt = 0; nt < 4; ++nt) {
      const int krow = nt * 16 + c16;
#pragma unroll
      for (int ks = 0; ks < 3; ++ks) {
        const int d = ks * 32 + quad * 8;
        bf16x8 kh = {}, kl = {};
        if (d < 80) {
          kh = *(const bf16x8*)&sKh[cur][krow * 80 + d];
          kl = *(const bf16x8*)&sKl[cur][krow * 80 + d];
        }
        sc0[nt] = __builtin_amdgcn_mfma_f32_16x16x32_bf16(kh, qh0[ks], sc0[nt], 0, 0, 0);
        sc0[nt] = __builtin_amdgcn_mfma_f32_16x16x32_bf16(kh, ql0[ks], sc0[nt], 0, 0, 0);
        sc0[nt] = __builtin_amdgcn_mfma_f32_16x16x32_bf16(kl, qh0[ks], sc0[nt], 0, 0, 0);
        sc1[nt] = __builtin_amdgcn_mfma_f32_16x16x32_bf16(kh, qh1[ks], sc1[nt], 0, 0, 0);
        sc1[nt] = __builtin_amdgcn_mfma_f32_16x16x32_bf16(kh, ql1[ks], sc1[nt], 0, 0, 0);
        sc1[nt] = __builtin_amdgcn_mfma_f32_16x16x32_bf16(kl, qh1[ks], sc1[nt], 0, 0, 0);
      }
    }
    __builtin_amdgcn_s_setprio(0);

    // ---- mask + online softmax per subtile, all in registers ----
    unsigned int pk0[4][4], pk1[4][4];
    float aR0[4], aR1[4];
    SMAX(sc0, m0, l0v, pk0, aR0, kb_lo0, kb_hi0);
    SMAX(sc1, m1, l1v, pk1, aR1, kb_lo1, kb_hi1);
#pragma unroll
    for (int dt = 0; dt < 5; ++dt) {
      f32x4 o = O0[dt];
      o[0] *= aR0[0]; o[1] *= aR0[1]; o[2] *= aR0[2]; o[3] *= aR0[3];
      O0[dt] = o;
      o = O1[dt];
      o[0] *= aR1[0]; o[1] *= aR1[1]; o[2] *= aR1[2]; o[3] *= aR1[3];
      O1[dt] = o;
    }

    // ---- PV: A = P via bpermute transpose, B = V^T (swizzled), V read once ----
#pragma unroll
    for (int ks = 0; ks < 2; ++ks) {
      union { unsigned int w[4]; bf16x8 v; } ph0u, pl0u, ph1u, pl1u;
      BUILD_P(pk0, ph0u, pl0u);
      BUILD_P(pk1, ph1u, pl1u);
      const int g = ks * 4 + quad;
      __builtin_amdgcn_s_setprio(1);
#pragma unroll
      for (int dt = 0; dt < 5; ++dt) {
        const int d = dt * 16 + c16;
        const int off = d * 64 + ((g ^ (d & 7)) * 8);
        bf16x8 vh = *(const bf16x8*)&sVh[cur][off];
        bf16x8 vl = *(const bf16x8*)&sVl[cur][off];
        O0[dt] = __builtin_amdgcn_mfma_f32_16x16x32_bf16(ph0u.v, vh, O0[dt], 0, 0, 0);
        O0[dt] = __builtin_amdgcn_mfma_f32_16x16x32_bf16(ph0u.v, vl, O0[dt], 0, 0, 0);
        O0[dt] = __builtin_amdgcn_mfma_f32_16x16x32_bf16(pl0u.v, vh, O0[dt], 0, 0, 0);
        O1[dt] = __builtin_amdgcn_mfma_f32_16x16x32_bf16(ph1u.v, vh, O1[dt], 0, 0, 0);
        O1[dt] = __builtin_amdgcn_mfma_f32_16x16x32_bf16(ph1u.v, vl, O1[dt], 0, 0, 0);
        O1[dt] = __builtin_amdgcn_mfma_f32_16x16x32_bf16(pl1u.v, vh, O1[dt], 0, 0, 0);
      }
      __builtin_amdgcn_s_setprio(0);
    }
    cur ^= 1;
  }

  // ---- epilogue: normalize + store o_hi (bf16), both subtiles ----
  const float inv0 = 1.0f / l0v;
  const float inv1 = 1.0f / l1v;
  float iR0[4], iR1[4];
#pragma unroll
  for (int r = 0; r < 4; ++r) {
    iR0[r] = __uint_as_float((unsigned)__builtin_amdgcn_ds_bpermute(
                 (quad * 4 + r) << 2, __float_as_int(inv0)));
    iR1[r] = __uint_as_float((unsigned)__builtin_amdgcn_ds_bpermute(
                 (quad * 4 + r) << 2, __float_as_int(inv1)));
  }
#pragma unroll
  for (int dt = 0; dt < 5; ++dt)
#pragma unroll
    for (int r = 0; r < 4; ++r) {
      const int row0 = r0 + wave * 16 + quad * 4 + r;
      ohi[(size_t)row0 * HID + h * HD + dt * 16 + c16] = f2bf(O0[dt][r] * iR0[r]);
      ohi[(size_t)(row0 + 64) * HID + h * HD + dt * 16 + c16] = f2bf(O1[dt][r] * iR1[r]);
    }
}

// ---------------- host launcher ---------------------------------------------
extern "C" void kernel_launch(void* const* d_in, const int* in_sizes, int n_in,
                              void* d_out, int out_size, void* d_ws, size_t ws_size,
                              hipStream_t stream) {
  const float* x      = (const float*)d_in[0];
  const int*   cu     = (const int*)d_in[1];
  const float* cs     = (const float*)d_in[2];
  const float* sn     = (const float*)d_in[3];
  const float* w_qkv  = (const float*)d_in[4];
  const float* b_qkv  = (const float*)d_in[5];
  const float* w_proj = (const float*)d_in[6];
  const float* b_proj = (const float*)d_in[7];
  float* out = (float*)d_out;

  char* ws = (char*)d_ws;
  float*          qf     = (float*)(ws + 0);
  float*          kf     = (float*)(ws + 20971520ULL);
  unsigned short* vthi   = (unsigned short*)(ws + 20971520ULL);
  unsigned short* vtlo   = (unsigned short*)(ws + 31457280ULL);
  float*          vf     = (float*)(ws + 41943040ULL);
  unsigned short* o_hi   = (unsigned short*)(ws + 41943040ULL);
  unsigned short* x_hi   = (unsigned short*)(ws + 62914560ULL);
  unsigned short* khi    = (unsigned short*)(ws + 62914560ULL);
  unsigned short* klo    = (unsigned short*)(ws + 73400320ULL);
  unsigned short* wqt_hi = (unsigned short*)(ws + 83886080ULL);
  unsigned short* wqt_lo = (unsigned short*)(ws + 93716480ULL);
  unsigned short* wpt_hi = (unsigned short*)(ws + 103546880ULL);
  unsigned short* wpt_lo = (unsigned short*)(ws + 106823680ULL);
  unsigned int*   ctr    = (unsigned int*)(ws + 83886080ULL);  // over dead wqt_hi

  split_hi_kernel<<<5120, 256, 0, stream>>>(x, x_hi, 1310720);
  tsplit_kernel<<<dim3(120, 40), 256, 0, stream>>>(w_qkv, wqt_hi, wqt_lo, 1280, 3840);
  tsplit_kernel<<<dim3(40, 40), 256, 0, stream>>>(w_proj, wpt_hi, wpt_lo, 1280, 1280);
  gemm128_x2<<<dim3(30, 32), 256, 0, stream>>>(x_hi, wqt_hi, wqt_lo, b_qkv,
                                               qf, kf, vf, 4096, 3840, 1280);
  rope_pack_kernel<<<dim3(64, 16), 256, 0, stream>>>(qf, kf, cs, sn, khi, klo);
  vt_pack_kernel<<<dim3(64, 16), 256, 0, stream>>>(vf, vthi, vtlo, ctr);
  attn_kernel<<<512, 256, 0, stream>>>(qf, khi, klo, vthi, vtlo, cu, o_hi);
  gemm128_x2<<<dim3(10, 32), 256, 0, stream>>>(o_hi, wpt_hi, wpt_lo, b_proj,
                                               out, nullptr, nullptr, 4096, 1280, 1280);
}

// Round 2
// 410.165 us; speedup vs baseline: 1.0005x; 1.0005x over previous
//
#include <hip/hip_runtime.h>
#include <cstdint>
#include <cstddef>

typedef __bf16 bf16x8 __attribute__((ext_vector_type(8)));
typedef float f32x4 __attribute__((ext_vector_type(4)));

#define SEQ   4096
#define HID   1280
#define NH    16
#define HD    80

__device__ __forceinline__ unsigned short f2bf(float f) {
  unsigned int u = __float_as_uint(f);
  unsigned int r = u + 0x7FFFu + ((u >> 16) & 1u);   // RNE
  return (unsigned short)(r >> 16);
}
__device__ __forceinline__ float bf2f(unsigned short h) {
  return __uint_as_float(((unsigned int)h) << 16);
}
__device__ __forceinline__ __bf16 us2bf(unsigned short u) {
  union { unsigned short s; __bf16 b; } c; c.s = u; return c.b;
}
__device__ __forceinline__ void dma16(const void* g, void* l) {
  __builtin_amdgcn_global_load_lds((const __attribute__((address_space(1))) unsigned int*)g,
                                   (__attribute__((address_space(3))) unsigned int*)l, 16, 0, 0);
}

// ---------------- split: f32 -> bf16 hi only ---------------------------------
__global__ __launch_bounds__(256) void split_hi_kernel(const float* __restrict__ x,
                                                       unsigned short* __restrict__ hi,
                                                       int n4) {
  int i = blockIdx.x * 256 + threadIdx.x;
  if (i >= n4) return;
  float4 v = *((const float4*)x + i);
  *((ushort4*)hi + i) = make_ushort4(f2bf(v.x), f2bf(v.y), f2bf(v.z), f2bf(v.w));
}

// ---------------- transpose + split weights (hi/lo) --------------------------
__global__ __launch_bounds__(256) void tsplit_kernel(const float* __restrict__ W,
                                                     unsigned short* __restrict__ Thi,
                                                     unsigned short* __restrict__ Tlo,
                                                     int K, int N) {
  __shared__ float tile[32][33];
  int n0 = blockIdx.x * 32, k0 = blockIdx.y * 32;
  int tx = threadIdx.x & 31, ty = threadIdx.x >> 5;
#pragma unroll
  for (int i = 0; i < 32; i += 8)
    tile[ty + i][tx] = W[(size_t)(k0 + ty + i) * N + n0 + tx];
  __syncthreads();
#pragma unroll
  for (int i = 0; i < 32; i += 8) {
    float v = tile[tx][ty + i];
    size_t idx = (size_t)(n0 + ty + i) * K + (size_t)(k0 + tx);
    unsigned short h = f2bf(v);
    Thi[idx] = h;
    Tlo[idx] = f2bf(v - bf2f(h));
  }
}

// ---------------- 128x128 DMA GEMM, 2-term (A bf16, B hi/lo) -----------------
__global__ __launch_bounds__(256, 3) void gemm128_x2(
    const unsigned short* __restrict__ A, const unsigned short* __restrict__ Bh,
    const unsigned short* __restrict__ Bl, const float* __restrict__ bias,
    float* __restrict__ out0, float* __restrict__ out1, float* __restrict__ out2,
    int M, int N, int K) {
  __shared__ __align__(16) unsigned short sALL[3 * 8192];  // [A | Bh | Bl]

  const int t = threadIdx.x;
  const int lane = t & 63, wave = t >> 6;
  const int c16 = lane & 15, quad = lane >> 4;
  const int bm = blockIdx.y * 128, bn = blockIdx.x * 128;
  const int wr = (wave >> 1) * 64, wc = (wave & 1) * 64;
  const int lrow = lane >> 3;
  const int lswz = (lane & 7) ^ lrow;

  f32x4 acc[4][4];
#pragma unroll
  for (int i = 0; i < 4; ++i)
#pragma unroll
    for (int j = 0; j < 4; ++j) acc[i][j] = (f32x4){0.f, 0.f, 0.f, 0.f};

  // 48 DMA units/iter, 12 per wave; unit ua: arr = ua>>4 (0=A,1=Bh,2=Bl)
  const unsigned short* gp[12];
#pragma unroll
  for (int i = 0; i < 12; ++i) {
    const int ua = wave * 12 + i;
    const int arr = ua >> 4, sub = ua & 15;
    const unsigned short* g = (arr == 0) ? A : (arr == 1) ? Bh : Bl;
    const int rowg = ((arr == 0) ? bm : bn) + sub * 8 + lrow;
    gp[i] = g + (size_t)rowg * K + lswz * 8;
  }

  for (int k0 = 0; k0 < K; k0 += 64) {
    __syncthreads();
#pragma unroll
    for (int i = 0; i < 12; ++i)
      dma16(gp[i] + k0, &sALL[(wave * 12 + i) * 512]);
    __syncthreads();
#pragma unroll
    for (int ks = 0; ks < 2; ++ks) {
      bf16x8 a[4], bh[4], bl[4];
#pragma unroll
      for (int mi = 0; mi < 4; ++mi) {
        const int row = wr + mi * 16 + c16;
        const int off = row * 64 + (((ks * 4 + quad) ^ (row & 7)) * 8);
        a[mi] = *(const bf16x8*)&sALL[off];
      }
#pragma unroll
      for (int ni = 0; ni < 4; ++ni) {
        const int row = wc + ni * 16 + c16;
        const int off = row * 64 + (((ks * 4 + quad) ^ (row & 7)) * 8);
        bh[ni] = *(const bf16x8*)&sALL[8192 + off];
        bl[ni] = *(const bf16x8*)&sALL[16384 + off];
      }
#pragma unroll
      for (int mi = 0; mi < 4; ++mi)
#pragma unroll
        for (int ni = 0; ni < 4; ++ni) {
          acc[mi][ni] = __builtin_amdgcn_mfma_f32_16x16x32_bf16(a[mi], bh[ni], acc[mi][ni], 0, 0, 0);
          acc[mi][ni] = __builtin_amdgcn_mfma_f32_16x16x32_bf16(a[mi], bl[ni], acc[mi][ni], 0, 0, 0);
        }
    }
  }
  // epilogue: C/D layout col=c16, row=quad*4+r
#pragma unroll
  for (int ni = 0; ni < 4; ++ni) {
    int colg = bn + wc + ni * 16 + c16;
    float bv = bias[colg];
    float* op;
    int c = colg;
    if (c < 1280) op = out0;
    else if (c < 2560) { op = out1; c -= 1280; }
    else { op = out2; c -= 2560; }
#pragma unroll
    for (int mi = 0; mi < 4; ++mi)
#pragma unroll
      for (int r = 0; r < 4; ++r) {
        int rowg = bm + wr + mi * 16 + quad * 4 + r;
        op[(size_t)rowg * 1280 + c] = acc[mi][ni][r] + bv;
      }
  }
}

// ---------------- RoPE on q (in place, f32) + k -> packed bf16 hi/lo ---------
__global__ __launch_bounds__(256) void rope_pack_kernel(
    float* __restrict__ qf, const float* __restrict__ kf,
    const float* __restrict__ cs, const float* __restrict__ sn,
    unsigned short* __restrict__ khi, unsigned short* __restrict__ klo) {
  const int h = blockIdx.y;
  const int s = blockIdx.x * 64 + (threadIdx.x >> 2);
  const int p = threadIdx.x & 3;
  float* qrow = qf + (size_t)s * HID + h * HD;
  const float* krow = kf + (size_t)s * HID + h * HD;
  const float* cr = cs + (size_t)s * HD;
  const float* sr = sn + (size_t)s * HD;
  unsigned short* kh = khi + ((size_t)h * SEQ + s) * HD;
  unsigned short* kl = klo + ((size_t)h * SEQ + s) * HD;
#pragma unroll
  for (int j = 0; j < 10; ++j) {
    int d = 10 * p + j;           // 0..39
    float c0 = cr[d], s0 = sr[d], c1 = cr[d + 40], s1 = sr[d + 40];
    float q0 = qrow[d], q1 = qrow[d + 40];
    qrow[d]      = q0 * c0 - q1 * s0;
    qrow[d + 40] = q1 * c1 + q0 * s1;
    float k0 = krow[d], k1 = krow[d + 40];
    float kn0 = k0 * c0 - k1 * s0;
    float kn1 = k1 * c1 + k0 * s1;
    unsigned short h0 = f2bf(kn0), h1 = f2bf(kn1);
    kh[d] = h0;      kl[d] = f2bf(kn0 - bf2f(h0));
    kh[d + 40] = h1; kl[d + 40] = f2bf(kn1 - bf2f(h1));
  }
}

// ---------------- pack V^T: f32 [s][1280] -> bf16 hi/lo [h][80][4096] --------
__global__ __launch_bounds__(256) void vt_pack_kernel(const float* __restrict__ vf,
                                                      unsigned short* __restrict__ vthi,
                                                      unsigned short* __restrict__ vtlo) {
  __shared__ unsigned short sTh[80][72];
  __shared__ unsigned short sTl[80][72];
  const int h = blockIdx.y;
  const int s0 = blockIdx.x * 64;
  const int t = threadIdx.x;
  {
    int row = t >> 2, p = (t & 3) * 20;
    const float* src = vf + (size_t)(s0 + row) * HID + h * HD + p;
#pragma unroll
    for (int i = 0; i < 5; ++i) {
      float4 v = *(const float4*)(src + 4 * i);
      float vv[4] = {v.x, v.y, v.z, v.w};
#pragma unroll
      for (int j = 0; j < 4; ++j) {
        int d = p + 4 * i + j;
        unsigned short hu = f2bf(vv[j]);
        sTh[d][row] = hu;
        sTl[d][row] = f2bf(vv[j] - bf2f(hu));
      }
    }
  }
  __syncthreads();
  if (t < 160) {
    int d = t >> 1, half = (t & 1) * 32;
    size_t base = (size_t)(h * HD + d) * SEQ + s0 + half;
#pragma unroll
    for (int i = 0; i < 8; ++i) {
      *(ushort4*)&vthi[base + 4 * i] = *(ushort4*)&sTh[d][half + 4 * i];
      *(ushort4*)&vtlo[base + 4 * i] = *(ushort4*)&sTl[d][half + 4 * i];
    }
  }
}

// ---------------- attention ---------------------------------------------------
// 1024 blocks of 2 waves (128 thr). Unit u: head = u>>6, 64-row q-tile = u&63.
// XCD-local static map: u = (b&7)*128 + (b>>3) -> XCD x sees heads 2x,2x+1.
// Each wave owns TWO 16-row q-subtiles (rows +0/+32) sharing K/V LDS reads.
// Single-buffered K/V (40960 B exactly -> 4 blocks/CU, desynced barrier
// domains). Two-barrier half-chunk pipeline: K(i+1) DMA rides PV(i),
// V(i+1) DMA rides QK(i+1)+softmax.

#define SMAX(SC, MI, LI, PK, AR, KBLO, KBHI)                                   \
  do {                                                                         \
    float mx = -1e30f;                                                         \
    _Pragma("unroll") for (int nt = 0; nt < 4; ++nt)                           \
        _Pragma("unroll") for (int r = 0; r < 4; ++r) {                        \
      const int kg = ck + nt * 16 + quad * 4 + r;                              \
      const bool ok = (kg >= (KBLO)) && (kg < (KBHI));                         \
      float v = ok ? SC[nt][r] : -1e30f;                                       \
      SC[nt][r] = v;                                                           \
      mx = fmaxf(mx, v);                                                       \
    }                                                                          \
    mx = fmaxf(mx, __shfl_xor(mx, 16));                                        \
    mx = fmaxf(mx, __shfl_xor(mx, 32));                                        \
    const float mnew = fmaxf(MI, mx);                                          \
    const float alpha = __expf(MI - mnew);                                     \
    float ps = 0.f;                                                            \
    _Pragma("unroll") for (int nt = 0; nt < 4; ++nt)                           \
        _Pragma("unroll") for (int r = 0; r < 4; ++r) {                        \
      const float s = SC[nt][r];                                               \
      const float p = (s > -1e29f) ? __expf(s - mnew) : 0.f;                   \
      ps += p;                                                                 \
      const unsigned int pu = __float_as_uint(p);                              \
      const unsigned short ph_ = (unsigned short)(pu >> 16);                   \
      const unsigned short pl_ = f2bf(p - bf2f(ph_));                          \
      PK[nt][r] = (unsigned int)ph_ | ((unsigned int)pl_ << 16);               \
    }                                                                          \
    ps += __shfl_xor(ps, 16);                                                  \
    ps += __shfl_xor(ps, 32);                                                  \
    LI = LI * alpha + ps;                                                      \
    MI = mnew;                                                                 \
    _Pragma("unroll") for (int r = 0; r < 4; ++r)                              \
        AR[r] = __uint_as_float((unsigned)__builtin_amdgcn_ds_bpermute(        \
            (quad * 4 + r) << 2, __float_as_int(alpha)));                      \
  } while (0)

#define BUILD_P(PK, PHU, PLU)                                                  \
  do {                                                                         \
    unsigned int vj[8];                                                        \
    _Pragma("unroll") for (int j = 0; j < 8; ++j) {                            \
      const int addr = (j < 4) ? addrA : addrB;                                \
      const int r = j & 3;                                                     \
      const int v0 = __builtin_amdgcn_ds_bpermute(addr, (int)PK[2 * ks + 0][r]); \
      const int v1 = __builtin_amdgcn_ds_bpermute(addr, (int)PK[2 * ks + 1][r]); \
      vj[j] = (unsigned int)((quad & 2) ? v1 : v0);                            \
    }                                                                          \
    PHU.w[0] = __builtin_amdgcn_perm(vj[1], vj[0], 0x05040100u);               \
    PHU.w[1] = __builtin_amdgcn_perm(vj[3], vj[2], 0x05040100u);               \
    PHU.w[2] = __builtin_amdgcn_perm(vj[5], vj[4], 0x05040100u);               \
    PHU.w[3] = __builtin_amdgcn_perm(vj[7], vj[6], 0x05040100u);               \
    PLU.w[0] = __builtin_amdgcn_perm(vj[1], vj[0], 0x07060302u);               \
    PLU.w[1] = __builtin_amdgcn_perm(vj[3], vj[2], 0x07060302u);               \
    PLU.w[2] = __builtin_amdgcn_perm(vj[5], vj[4], 0x07060302u);               \
    PLU.w[3] = __builtin_amdgcn_perm(vj[7], vj[6], 0x07060302u);               \
  } while (0)

__global__ __launch_bounds__(128, 2) void attn_kernel(
    const float* __restrict__ qf, const unsigned short* __restrict__ khi,
    const unsigned short* __restrict__ klo, const unsigned short* __restrict__ vthi,
    const unsigned short* __restrict__ vtlo, const int* __restrict__ cu,
    unsigned short* __restrict__ ohi) {
  __shared__ __align__(16) unsigned short sKh[5120], sKl[5120];
  __shared__ __align__(16) unsigned short sVh[5120], sVl[5120];
  // total LDS = 4*5120*2 = 40960 B exactly -> 4 blocks/CU

  const int t = threadIdx.x;
  const int lane = t & 63, wave = t >> 6;           // 2 waves
  const int c16 = lane & 15, quad = lane >> 4;
  const int lr8 = lane >> 3;
  const int vswz = (lane & 7) ^ lr8;
  const int addrA = ((((2 * quad) & 3) * 16) + c16) << 2;
  const int addrB = ((((2 * quad + 1) & 3) * 16) + c16) << 2;

  // XCD-local static unit map (1024 = 8 * 128)
  const unsigned int u = (blockIdx.x & 7) * 128 + (blockIdx.x >> 3);
  const int h = (int)(u >> 6);
  const int r0 = (int)(u & 63u) * 64;

  int cu_r[9];
#pragma unroll
  for (int i = 0; i < 9; ++i) cu_r[i] = cu[i];

  const int q0 = r0 + wave * 16 + c16;       // subtile-0 query row of this lane
  const int q1 = q0 + 32;                    // subtile-1 query row
  int sq0 = 0, sq1 = 0, sg0 = 0, sg1 = 0;
#pragma unroll
  for (int i = 1; i < 8; ++i) {
    sq0 += (q0 >= cu_r[i]) ? 1 : 0;
    sq1 += (q1 >= cu_r[i]) ? 1 : 0;
    sg0 += (r0 >= cu_r[i]) ? 1 : 0;
    sg1 += (r0 + 63 >= cu_r[i]) ? 1 : 0;
  }
  const int kb_lo0 = cu_r[sq0], kb_hi0 = cu_r[sq0 + 1];
  const int kb_lo1 = cu_r[sq1], kb_hi1 = cu_r[sq1 + 1];
  const int ck0 = cu_r[sg0] & ~63;
  const int kend = cu_r[sg1 + 1];
  const int nchunk = (kend - ck0 + 63) >> 6;

  // Q fragments (B-operand layout), scale folded; both subtiles
  const float qsc = 0.11180339887498949f;
  bf16x8 qh0[3], ql0[3], qh1[3], ql1[3];
  {
    const float* qrowA = qf + (size_t)q0 * HID + h * HD;
    const float* qrowB = qf + (size_t)q1 * HID + h * HD;
#pragma unroll
    for (int ks = 0; ks < 3; ++ks) {
      const int d = ks * 32 + quad * 8;
      bf16x8 hA = {}, lA = {}, hB = {}, lB = {};
      if (d < 80) {
        float4 a0 = *(const float4*)(qrowA + d);
        float4 a1 = *(const float4*)(qrowA + d + 4);
        float4 b0 = *(const float4*)(qrowB + d);
        float4 b1 = *(const float4*)(qrowB + d + 4);
        float va[8] = {a0.x, a0.y, a0.z, a0.w, a1.x, a1.y, a1.z, a1.w};
        float vb[8] = {b0.x, b0.y, b0.z, b0.w, b1.x, b1.y, b1.z, b1.w};
#pragma unroll
        for (int j = 0; j < 8; ++j) {
          float v = va[j] * qsc;
          unsigned short hu = f2bf(v);
          hA[j] = us2bf(hu); lA[j] = us2bf(f2bf(v - bf2f(hu)));
          v = vb[j] * qsc;
          hu = f2bf(v);
          hB[j] = us2bf(hu); lB[j] = us2bf(f2bf(v - bf2f(hu)));
        }
      }
      qh0[ks] = hA; ql0[ks] = lA; qh1[ks] = hB; ql1[ks] = lB;
    }
  }

  f32x4 O0[5], O1[5];
#pragma unroll
  for (int dt = 0; dt < 5; ++dt) {
    O0[dt] = (f32x4){0.f, 0.f, 0.f, 0.f};
    O1[dt] = (f32x4){0.f, 0.f, 0.f, 0.f};
  }
  float m0 = -1e30f, l0v = 0.f, m1 = -1e30f, l1v = 0.f;

  // stage K of chunk ck: wave0 -> khi, wave1 -> klo (10 dma16 each, contiguous)
  auto STAGE_K = [&](int ck) {
    const unsigned short* gk = (wave & 1) ? klo : khi;
    unsigned short* lk = (wave & 1) ? sKl : sKh;
    const size_t kb = ((size_t)h * SEQ + ck) * 80 + lane * 8;
#pragma unroll
    for (int i2 = 0; i2 < 10; ++i2) dma16(gk + kb + i2 * 512, lk + i2 * 512);
  };
  // stage V of chunk ck: wave0 -> vthi, wave1 -> vtlo (10 dma16 each)
  auto STAGE_V = [&](int ck) {
    const unsigned short* gv = (wave & 1) ? vtlo : vthi;
    unsigned short* lv = (wave & 1) ? sVl : sVh;
#pragma unroll
    for (int i2 = 0; i2 < 10; ++i2)
      dma16(gv + (size_t)(h * HD + 8 * i2 + lr8) * SEQ + ck + vswz * 8, lv + i2 * 512);
  };

  STAGE_K(ck0);
  STAGE_V(ck0);
  __syncthreads();   // drain K(0)+V(0)

  for (int ci = 0; ci < nchunk; ++ci) {
    const int ck = ck0 + ci * 64;

    // ---- QK: S^T = K * Q^T for BOTH subtiles, K fragments read once ----
    f32x4 sc0[4], sc1[4];
#pragma unroll
    for (int nt = 0; nt < 4; ++nt) {
      sc0[nt] = (f32x4){0.f, 0.f, 0.f, 0.f};
      sc1[nt] = (f32x4){0.f, 0.f, 0.f, 0.f};
    }
    __builtin_amdgcn_s_setprio(1);
#pragma unroll
    for (int nt = 0; nt < 4; ++nt) {
      const int krow = nt * 16 + c16;
#pragma unroll
      for (int ks = 0; ks < 3; ++ks) {
        const int d = ks * 32 + quad * 8;
        bf16x8 kh = {}, kl = {};
        if (d < 80) {
          kh = *(const bf16x8*)&sKh[krow * 80 + d];
          kl = *(const bf16x8*)&sKl[krow * 80 + d];
        }
        sc0[nt] = __builtin_amdgcn_mfma_f32_16x16x32_bf16(kh, qh0[ks], sc0[nt], 0, 0, 0);
        sc0[nt] = __builtin_amdgcn_mfma_f32_16x16x32_bf16(kh, ql0[ks], sc0[nt], 0, 0, 0);
        sc0[nt] = __builtin_amdgcn_mfma_f32_16x16x32_bf16(kl, qh0[ks], sc0[nt], 0, 0, 0);
        sc1[nt] = __builtin_amdgcn_mfma_f32_16x16x32_bf16(kh, qh1[ks], sc1[nt], 0, 0, 0);
        sc1[nt] = __builtin_amdgcn_mfma_f32_16x16x32_bf16(kh, ql1[ks], sc1[nt], 0, 0, 0);
        sc1[nt] = __builtin_amdgcn_mfma_f32_16x16x32_bf16(kl, qh1[ks], sc1[nt], 0, 0, 0);
      }
    }
    __builtin_amdgcn_s_setprio(0);

    // ---- mask + online softmax per subtile, all in registers ----
    unsigned int pk0[4][4], pk1[4][4];
    float aR0[4], aR1[4];
    SMAX(sc0, m0, l0v, pk0, aR0, kb_lo0, kb_hi0);
    SMAX(sc1, m1, l1v, pk1, aR1, kb_lo1, kb_hi1);
#pragma unroll
    for (int dt = 0; dt < 5; ++dt) {
      f32x4 o = O0[dt];
      o[0] *= aR0[0]; o[1] *= aR0[1]; o[2] *= aR0[2]; o[3] *= aR0[3];
      O0[dt] = o;
      o = O1[dt];
      o[0] *= aR1[0]; o[1] *= aR1[1]; o[2] *= aR1[2]; o[3] *= aR1[3];
      O1[dt] = o;
    }

    // ---- barrier A: K reads of chunk ci done; V(ci) DMA drained ----
    __syncthreads();
    if (ci + 1 < nchunk) STAGE_K(ck + 64);   // rides PV below

    // ---- PV: A = P via bpermute transpose, B = V^T (swizzled), V read once --
#pragma unroll
    for (int ks = 0; ks < 2; ++ks) {
      union { unsigned int w[4]; bf16x8 v; } ph0u, pl0u, ph1u, pl1u;
      BUILD_P(pk0, ph0u, pl0u);
      BUILD_P(pk1, ph1u, pl1u);
      const int g = ks * 4 + quad;
      __builtin_amdgcn_s_setprio(1);
#pragma unroll
      for (int dt = 0; dt < 5; ++dt) {
        const int d = dt * 16 + c16;
        const int off = d * 64 + ((g ^ (d & 7)) * 8);
        bf16x8 vh = *(const bf16x8*)&sVh[off];
        bf16x8 vl = *(const bf16x8*)&sVl[off];
        O0[dt] = __builtin_amdgcn_mfma_f32_16x16x32_bf16(ph0u.v, vh, O0[dt], 0, 0, 0);
        O0[dt] = __builtin_amdgcn_mfma_f32_16x16x32_bf16(ph0u.v, vl, O0[dt], 0, 0, 0);
        O0[dt] = __builtin_amdgcn_mfma_f32_16x16x32_bf16(pl0u.v, vh, O0[dt], 0, 0, 0);
        O1[dt] = __builtin_amdgcn_mfma_f32_16x16x32_bf16(ph1u.v, vh, O1[dt], 0, 0, 0);
        O1[dt] = __builtin_amdgcn_mfma_f32_16x16x32_bf16(ph1u.v, vl, O1[dt], 0, 0, 0);
        O1[dt] = __builtin_amdgcn_mfma_f32_16x16x32_bf16(pl1u.v, vh, O1[dt], 0, 0, 0);
      }
      __builtin_amdgcn_s_setprio(0);
    }

    // ---- barrier B: V reads of chunk ci done; K(ci+1) DMA drained ----
    __syncthreads();
    if (ci + 1 < nchunk) STAGE_V(ck + 64);   // rides next QK + softmax
  }

  // ---- epilogue: normalize + store o_hi (bf16), both subtiles ----
  const float inv0 = 1.0f / l0v;
  const float inv1 = 1.0f / l1v;
  float iR0[4], iR1[4];
#pragma unroll
  for (int r = 0; r < 4; ++r) {
    iR0[r] = __uint_as_float((unsigned)__builtin_amdgcn_ds_bpermute(
                 (quad * 4 + r) << 2, __float_as_int(inv0)));
    iR1[r] = __uint_as_float((unsigned)__builtin_amdgcn_ds_bpermute(
                 (quad * 4 + r) << 2, __float_as_int(inv1)));
  }
#pragma unroll
  for (int dt = 0; dt < 5; ++dt)
#pragma unroll
    for (int r = 0; r < 4; ++r) {
      const int row0 = r0 + wave * 16 + quad * 4 + r;
      ohi[(size_t)row0 * HID + h * HD + dt * 16 + c16] = f2bf(O0[dt][r] * iR0[r]);
      ohi[(size_t)(row0 + 32) * HID + h * HD + dt * 16 + c16] = f2bf(O1[dt][r] * iR1[r]);
    }
}

// ---------------- host launcher ---------------------------------------------
extern "C" void kernel_launch(void* const* d_in, const int* in_sizes, int n_in,
                              void* d_out, int out_size, void* d_ws, size_t ws_size,
                              hipStream_t stream) {
  const float* x      = (const float*)d_in[0];
  const int*   cu     = (const int*)d_in[1];
  const float* cs     = (const float*)d_in[2];
  const float* sn     = (const float*)d_in[3];
  const float* w_qkv  = (const float*)d_in[4];
  const float* b_qkv  = (const float*)d_in[5];
  const float* w_proj = (const float*)d_in[6];
  const float* b_proj = (const float*)d_in[7];
  float* out = (float*)d_out;

  char* ws = (char*)d_ws;
  float*          qf     = (float*)(ws + 0);
  float*          kf     = (float*)(ws + 20971520ULL);
  unsigned short* vthi   = (unsigned short*)(ws + 20971520ULL);
  unsigned short* vtlo   = (unsigned short*)(ws + 31457280ULL);
  float*          vf     = (float*)(ws + 41943040ULL);
  unsigned short* o_hi   = (unsigned short*)(ws + 41943040ULL);
  unsigned short* x_hi   = (unsigned short*)(ws + 62914560ULL);
  unsigned short* khi    = (unsigned short*)(ws + 62914560ULL);
  unsigned short* klo    = (unsigned short*)(ws + 73400320ULL);
  unsigned short* wqt_hi = (unsigned short*)(ws + 83886080ULL);
  unsigned short* wqt_lo = (unsigned short*)(ws + 93716480ULL);
  unsigned short* wpt_hi = (unsigned short*)(ws + 103546880ULL);
  unsigned short* wpt_lo = (unsigned short*)(ws + 106823680ULL);

  split_hi_kernel<<<5120, 256, 0, stream>>>(x, x_hi, 1310720);
  tsplit_kernel<<<dim3(120, 40), 256, 0, stream>>>(w_qkv, wqt_hi, wqt_lo, 1280, 3840);
  tsplit_kernel<<<dim3(40, 40), 256, 0, stream>>>(w_proj, wpt_hi, wpt_lo, 1280, 1280);
  gemm128_x2<<<dim3(30, 32), 256, 0, stream>>>(x_hi, wqt_hi, wqt_lo, b_qkv,
                                               qf, kf, vf, 4096, 3840, 1280);
  rope_pack_kernel<<<dim3(64, 16), 256, 0, stream>>>(qf, kf, cs, sn, khi, klo);
  vt_pack_kernel<<<dim3(64, 16), 256, 0, stream>>>(vf, vthi, vtlo);
  attn_kernel<<<1024, 128, 0, stream>>>(qf, khi, klo, vthi, vtlo, cu, o_hi);
  gemm128_x2<<<dim3(10, 32), 256, 0, stream>>>(o_hi, wpt_hi, wpt_lo, b_proj,
                                               out, nullptr, nullptr, 4096, 1280, 1280);
}

// Round 5
// 369.027 us; speedup vs baseline: 1.1120x; 1.1115x over previous
//
#include <hip/hip_runtime.h>
#include <cstdint>
#include <cstddef>

typedef __bf16 bf16x8 __attribute__((ext_vector_type(8)));
typedef float f32x4 __attribute__((ext_vector_type(4)));
typedef float f32x16 __attribute__((ext_vector_type(16)));
typedef unsigned short u16x8 __attribute__((ext_vector_type(8)));

#define SEQ   4096
#define HID   1280
#define NH    16
#define HD    80

__device__ __forceinline__ unsigned short f2bf(float f) {
  unsigned int u = __float_as_uint(f);
  unsigned int r = u + 0x7FFFu + ((u >> 16) & 1u);   // RNE
  return (unsigned short)(r >> 16);
}
__device__ __forceinline__ float bf2f(unsigned short h) {
  return __uint_as_float(((unsigned int)h) << 16);
}
__device__ __forceinline__ __bf16 us2bf(unsigned short u) {
  union { unsigned short s; __bf16 b; } c; c.s = u; return c.b;
}
__device__ __forceinline__ void dma16(const void* g, void* l) {
  __builtin_amdgcn_global_load_lds((const __attribute__((address_space(1))) unsigned int*)g,
                                   (__attribute__((address_space(3))) unsigned int*)l, 16, 0, 0);
}
__device__ __forceinline__ unsigned int cvtpk(float a, float b) {
  unsigned int w;
  asm("v_cvt_pk_bf16_f32 %0, %1, %2" : "=v"(w) : "v"(a), "v"(b));
  return w;
}
__device__ __forceinline__ float lo2f(unsigned int w) { return __uint_as_float(w << 16); }
__device__ __forceinline__ float hi2f(unsigned int w) { return __uint_as_float(w & 0xffff0000u); }

// ---------------- split: f32 -> bf16 hi only ---------------------------------
__global__ __launch_bounds__(256) void split_hi_kernel(const float* __restrict__ x,
                                                       unsigned short* __restrict__ hi,
                                                       int n4) {
  int i = blockIdx.x * 256 + threadIdx.x;
  if (i >= n4) return;
  float4 v = *((const float4*)x + i);
  *((ushort4*)hi + i) = make_ushort4(f2bf(v.x), f2bf(v.y), f2bf(v.z), f2bf(v.w));
}

// ---------------- transpose + split weights (hi/lo) --------------------------
__global__ __launch_bounds__(256) void tsplit_kernel(const float* __restrict__ W,
                                                     unsigned short* __restrict__ Thi,
                                                     unsigned short* __restrict__ Tlo,
                                                     int K, int N) {
  __shared__ float tile[32][33];
  int n0 = blockIdx.x * 32, k0 = blockIdx.y * 32;
  int tx = threadIdx.x & 31, ty = threadIdx.x >> 5;
#pragma unroll
  for (int i = 0; i < 32; i += 8)
    tile[ty + i][tx] = W[(size_t)(k0 + ty + i) * N + n0 + tx];
  __syncthreads();
#pragma unroll
  for (int i = 0; i < 32; i += 8) {
    float v = tile[tx][ty + i];
    size_t idx = (size_t)(n0 + ty + i) * K + (size_t)(k0 + tx);
    unsigned short h = f2bf(v);
    Thi[idx] = h;
    Tlo[idx] = f2bf(v - bf2f(h));
  }
}

// ---------------- 128x128 DMA GEMM, 2-term (A bf16, B hi/lo) -----------------
__global__ __launch_bounds__(256, 3) void gemm128_x2(
    const unsigned short* __restrict__ A, const unsigned short* __restrict__ Bh,
    const unsigned short* __restrict__ Bl, const float* __restrict__ bias,
    float* __restrict__ out0, float* __restrict__ out1, float* __restrict__ out2,
    int M, int N, int K) {
  __shared__ __align__(16) unsigned short sALL[3 * 8192];  // [A | Bh | Bl]

  const int t = threadIdx.x;
  const int lane = t & 63, wave = t >> 6;
  const int c16 = lane & 15, quad = lane >> 4;
  const int bm = blockIdx.y * 128, bn = blockIdx.x * 128;
  const int wr = (wave >> 1) * 64, wc = (wave & 1) * 64;
  const int lrow = lane >> 3;
  const int lswz = (lane & 7) ^ lrow;

  f32x4 acc[4][4];
#pragma unroll
  for (int i = 0; i < 4; ++i)
#pragma unroll
    for (int j = 0; j < 4; ++j) acc[i][j] = (f32x4){0.f, 0.f, 0.f, 0.f};

  const unsigned short* gp[12];
#pragma unroll
  for (int i = 0; i < 12; ++i) {
    const int ua = wave * 12 + i;
    const int arr = ua >> 4, sub = ua & 15;
    const unsigned short* g = (arr == 0) ? A : (arr == 1) ? Bh : Bl;
    const int rowg = ((arr == 0) ? bm : bn) + sub * 8 + lrow;
    gp[i] = g + (size_t)rowg * K + lswz * 8;
  }

  for (int k0 = 0; k0 < K; k0 += 64) {
    __syncthreads();
#pragma unroll
    for (int i = 0; i < 12; ++i)
      dma16(gp[i] + k0, &sALL[(wave * 12 + i) * 512]);
    __syncthreads();
#pragma unroll
    for (int ks = 0; ks < 2; ++ks) {
      bf16x8 a[4], bh[4], bl[4];
#pragma unroll
      for (int mi = 0; mi < 4; ++mi) {
        const int row = wr + mi * 16 + c16;
        const int off = row * 64 + (((ks * 4 + quad) ^ (row & 7)) * 8);
        a[mi] = *(const bf16x8*)&sALL[off];
      }
#pragma unroll
      for (int ni = 0; ni < 4; ++ni) {
        const int row = wc + ni * 16 + c16;
        const int off = row * 64 + (((ks * 4 + quad) ^ (row & 7)) * 8);
        bh[ni] = *(const bf16x8*)&sALL[8192 + off];
        bl[ni] = *(const bf16x8*)&sALL[16384 + off];
      }
#pragma unroll
      for (int mi = 0; mi < 4; ++mi)
#pragma unroll
        for (int ni = 0; ni < 4; ++ni) {
          acc[mi][ni] = __builtin_amdgcn_mfma_f32_16x16x32_bf16(a[mi], bh[ni], acc[mi][ni], 0, 0, 0);
          acc[mi][ni] = __builtin_amdgcn_mfma_f32_16x16x32_bf16(a[mi], bl[ni], acc[mi][ni], 0, 0, 0);
        }
    }
  }
#pragma unroll
  for (int ni = 0; ni < 4; ++ni) {
    int colg = bn + wc + ni * 16 + c16;
    float bv = bias[colg];
    float* op;
    int c = colg;
    if (c < 1280) op = out0;
    else if (c < 2560) { op = out1; c -= 1280; }
    else { op = out2; c -= 2560; }
#pragma unroll
    for (int mi = 0; mi < 4; ++mi)
#pragma unroll
      for (int r = 0; r < 4; ++r) {
        int rowg = bm + wr + mi * 16 + quad * 4 + r;
        op[(size_t)rowg * 1280 + c] = acc[mi][ni][r] + bv;
      }
  }
}

// ---------------- RoPE on q (in place, f32) + k -> packed bf16 hi/lo ---------
__global__ __launch_bounds__(256) void rope_pack_kernel(
    float* __restrict__ qf, const float* __restrict__ kf,
    const float* __restrict__ cs, const float* __restrict__ sn,
    unsigned short* __restrict__ khi, unsigned short* __restrict__ klo) {
  const int h = blockIdx.y;
  const int s = blockIdx.x * 64 + (threadIdx.x >> 2);
  const int p = threadIdx.x & 3;
  float* qrow = qf + (size_t)s * HID + h * HD;
  const float* krow = kf + (size_t)s * HID + h * HD;
  const float* cr = cs + (size_t)s * HD;
  const float* sr = sn + (size_t)s * HD;
  unsigned short* kh = khi + ((size_t)h * SEQ + s) * HD;
  unsigned short* kl = klo + ((size_t)h * SEQ + s) * HD;
#pragma unroll
  for (int j = 0; j < 10; ++j) {
    int d = 10 * p + j;           // 0..39
    float c0 = cr[d], s0 = sr[d], c1 = cr[d + 40], s1 = sr[d + 40];
    float q0 = qrow[d], q1 = qrow[d + 40];
    qrow[d]      = q0 * c0 - q1 * s0;
    qrow[d + 40] = q1 * c1 + q0 * s1;
    float k0 = krow[d], k1 = krow[d + 40];
    float kn0 = k0 * c0 - k1 * s0;
    float kn1 = k1 * c1 + k0 * s1;
    unsigned short h0 = f2bf(kn0), h1 = f2bf(kn1);
    kh[d] = h0;      kl[d] = f2bf(kn0 - bf2f(h0));
    kh[d + 40] = h1; kl[d + 40] = f2bf(kn1 - bf2f(h1));
  }
}

// ---------------- pack V^T: f32 [s][1280] -> bf16 hi/lo [h][80][4096] --------
__global__ __launch_bounds__(256) void vt_pack_kernel(const float* __restrict__ vf,
                                                      unsigned short* __restrict__ vthi,
                                                      unsigned short* __restrict__ vtlo) {
  __shared__ unsigned short sTh[80][72];
  __shared__ unsigned short sTl[80][72];
  const int h = blockIdx.y;
  const int s0 = blockIdx.x * 64;
  const int t = threadIdx.x;
  {
    int row = t >> 2, p = (t & 3) * 20;
    const float* src = vf + (size_t)(s0 + row) * HID + h * HD + p;
#pragma unroll
    for (int i = 0; i < 5; ++i) {
      float4 v = *(const float4*)(src + 4 * i);
      float vv[4] = {v.x, v.y, v.z, v.w};
#pragma unroll
      for (int j = 0; j < 4; ++j) {
        int d = p + 4 * i + j;
        unsigned short hu = f2bf(vv[j]);
        sTh[d][row] = hu;
        sTl[d][row] = f2bf(vv[j] - bf2f(hu));
      }
    }
  }
  __syncthreads();
  if (t < 160) {
    int d = t >> 1, half = (t & 1) * 32;
    size_t base = (size_t)(h * HD + d) * SEQ + s0 + half;
#pragma unroll
    for (int i = 0; i < 8; ++i) {
      *(ushort4*)&vthi[base + 4 * i] = *(ushort4*)&sTh[d][half + 4 * i];
      *(ushort4*)&vtlo[base + 4 * i] = *(ushort4*)&sTl[d][half + 4 * i];
    }
  }
}

// ---------------- attention (32x32 MFMA, queries on C-columns) ---------------
// 1024 blocks x 128 thr. Unit u: head = u>>6, 64-row q-tile = u&63.
// XCD-local map: u = (b&7)*128 + (b>>3). Wave w owns 32 queries (col=lane&31).
// S^T = K·Q^T (32x32x16), softmax state lane-local; P->B-frag via
// cvt_pk_bf16 + __shfl_xor(32) cross-half exchange (known-good semantics).
// O^T = V^T·P. K/V staged with per-row XOR-sigma granule permutation
// (conflict-free reads). Single-buffered K/V, 40960B LDS -> 4 blocks/CU,
// 2-barrier chunk pipeline.

#define MFMA32(A, B, C) __builtin_amdgcn_mfma_f32_32x32x16_bf16(A, B, C, 0, 0, 0)

__global__ __launch_bounds__(128, 2) void attn_kernel(
    const float* __restrict__ qf, const unsigned short* __restrict__ khi,
    const unsigned short* __restrict__ klo, const unsigned short* __restrict__ vthi,
    const unsigned short* __restrict__ vtlo, const int* __restrict__ cu,
    unsigned short* __restrict__ ohi) {
  __shared__ __align__(16) unsigned short sAll[20480];   // 40960 B exactly
  unsigned short* const sKh = sAll;                      // [64 key][80 d] sigma-perm
  unsigned short* const sKl = sAll + 5120;
  unsigned short* const sVh = sAll + 10240;              // [80 d][64 key] sigma-perm
  unsigned short* const sVl = sAll + 15360;

  const int t = threadIdx.x;
  const int lane = t & 63, wave = t >> 6;       // 2 waves
  const int ln5 = lane & 31;                    // query col / frag row
  const int hi  = lane >> 5;                    // k-group half
  const int ln7 = lane & 7;
  const int lr8 = lane >> 3;
  const int vswz = (lane & 7) ^ lr8;

  // XCD-local static unit map (1024 = 8 * 128)
  const unsigned int u = (blockIdx.x & 7) * 128 + (blockIdx.x >> 3);
  const int h = (int)(u >> 6);
  const int r0 = (int)(u & 63u) * 64;

  int cu_r[9];
#pragma unroll
  for (int i = 0; i < 9; ++i) cu_r[i] = cu[i];

  const int q_my = r0 + wave * 32 + ln5;        // this lane's query row
  int sq = 0, sg0 = 0, sg1 = 0;
#pragma unroll
  for (int i = 1; i < 8; ++i) {
    sq  += (q_my    >= cu_r[i]) ? 1 : 0;
    sg0 += (r0      >= cu_r[i]) ? 1 : 0;
    sg1 += (r0 + 63 >= cu_r[i]) ? 1 : 0;
  }
  const int kb_lo = cu_r[sq], kb_hi = cu_r[sq + 1];
  const int ck0 = cu_r[sg0] & ~63;
  const int kend = cu_r[sg1 + 1];
  const int nchunk = (kend - ck0 + 63) >> 6;

  // 16B-column table: position of logical granule (2c+hi) under XOR-sigma
  int ccol[5];
#pragma unroll
  for (int c = 0; c < 5; ++c)
    ccol[c] = (c < 4) ? ((((2 * c) + hi) ^ ln7) * 8) : ((8 + hi) * 8);

  // K DMA source offsets (shorts): granule G = i*64+lane -> key=G/10, pos=G%10,
  // logical col = pos^(key&7) for pos<8 else pos
  int koff[10];
#pragma unroll
  for (int i = 0; i < 10; ++i) {
    const int G = i * 64 + lane;
    const int key = (G * 205) >> 11;            // exact /10 for G<1024
    const int p = G - key * 10;
    const int cl = (p < 8) ? (p ^ (key & 7)) : p;
    koff[i] = key * 80 + cl * 8;
  }

  // Q fragments (B-operand: col=ln5=query, k = kt*16 + hi*8 + j), scale folded
  const float qsc = 0.11180339887498949f;
  bf16x8 qh[5], ql[5];
  {
    const float* qrow = qf + (size_t)q_my * HID + h * HD;
#pragma unroll
    for (int kt = 0; kt < 5; ++kt) {
      const int d0 = kt * 16 + hi * 8;
      float4 a0 = *(const float4*)(qrow + d0);
      float4 a1 = *(const float4*)(qrow + d0 + 4);
      float va[8] = {a0.x, a0.y, a0.z, a0.w, a1.x, a1.y, a1.z, a1.w};
      bf16x8 hf, lf;
#pragma unroll
      for (int j = 0; j < 8; ++j) {
        float v = va[j] * qsc;
        unsigned short hu = f2bf(v);
        hf[j] = us2bf(hu);
        lf[j] = us2bf(f2bf(v - bf2f(hu)));
      }
      qh[kt] = hf; ql[kt] = lf;
    }
  }

  f32x16 O0, O1, O2;
#pragma unroll
  for (int r = 0; r < 16; ++r) { O0[r] = 0.f; O1[r] = 0.f; O2[r] = 0.f; }
  float m_i = -1e30f, l_i = 0.f;

  // stage K of chunk ck (sigma-permuted source, linear LDS dest)
  auto STAGE_K = [&](int ck) {
    const unsigned short* gk = (wave & 1) ? klo : khi;
    unsigned short* lk = (wave & 1) ? sKl : sKh;
    const unsigned short* gb = gk + ((size_t)h * SEQ + ck) * 80;
#pragma unroll
    for (int i2 = 0; i2 < 10; ++i2) dma16(gb + koff[i2], lk + i2 * 512);
  };
  // stage V^T of chunk ck (sigma via pre-swizzled source cols)
  auto STAGE_V = [&](int ck) {
    const unsigned short* gv = (wave & 1) ? vtlo : vthi;
    unsigned short* lv = (wave & 1) ? sVl : sVh;
#pragma unroll
    for (int i2 = 0; i2 < 10; ++i2)
      dma16(gv + (size_t)(h * HD + 8 * i2 + lr8) * SEQ + ck + vswz * 8, lv + i2 * 512);
  };

  STAGE_K(ck0);
  STAGE_V(ck0);
  __syncthreads();

  for (int ci = 0; ci < nchunk; ++ci) {
    const int ck = ck0 + ci * 64;

    // ---- QK: S^T = K·Q^T, two 32-key tiles ----
    f32x16 sc0, sc1;
#pragma unroll
    for (int r = 0; r < 16; ++r) { sc0[r] = 0.f; sc1[r] = 0.f; }
    __builtin_amdgcn_s_setprio(1);
#pragma unroll
    for (int kd = 0; kd < 5; ++kd) {
      const int col = ccol[kd];
      bf16x8 kha = *(const bf16x8*)&sKh[ln5 * 80 + col];
      bf16x8 kla = *(const bf16x8*)&sKl[ln5 * 80 + col];
      bf16x8 khb = *(const bf16x8*)&sKh[(32 + ln5) * 80 + col];
      bf16x8 klb = *(const bf16x8*)&sKl[(32 + ln5) * 80 + col];
      sc0 = MFMA32(kha, qh[kd], sc0); sc1 = MFMA32(khb, qh[kd], sc1);
      sc0 = MFMA32(kha, ql[kd], sc0); sc1 = MFMA32(khb, ql[kd], sc1);
      sc0 = MFMA32(kla, qh[kd], sc0); sc1 = MFMA32(klb, qh[kd], sc1);
    }
    __builtin_amdgcn_s_setprio(0);

    // ---- mask + online softmax (all lane-local; key = (r&3)+8*(r>>2)+4*hi) --
    float mx = -1e30f;
#define MSK(SCV, KT2)                                                          \
    {                                                                          \
      const int kb = ck + (KT2) * 32 + 4 * hi;                                 \
      _Pragma("unroll")                                                        \
      for (int r = 0; r < 16; ++r) {                                           \
        const int kg = kb + (r & 3) + 8 * (r >> 2);                            \
        float v = (kg >= kb_lo && kg < kb_hi) ? SCV[r] : -1e30f;               \
        SCV[r] = v;                                                            \
        mx = fmaxf(mx, v);                                                     \
      }                                                                        \
    }
    MSK(sc0, 0)
    MSK(sc1, 1)
#undef MSK
    mx = fmaxf(mx, __shfl_xor(mx, 32));
    const float mnew = fmaxf(m_i, mx);
    const float alpha = __expf(m_i - mnew);
    float ps = 0.f;
#define EXPP(SCV)                                                              \
    _Pragma("unroll")                                                          \
    for (int r = 0; r < 16; ++r) {                                             \
      const float s = SCV[r];                                                  \
      const float p = (s > -1e29f) ? __expf(s - mnew) : 0.f;                   \
      ps += p;                                                                 \
      SCV[r] = p;                                                              \
    }
    EXPP(sc0)
    EXPP(sc1)
#undef EXPP
    ps += __shfl_xor(ps, 32);
    l_i = l_i * alpha + ps;
    m_i = mnew;
#pragma unroll
    for (int r = 0; r < 16; ++r) { O0[r] *= alpha; O1[r] *= alpha; O2[r] *= alpha; }

    // ---- barrier A: K reads done; V(ci) DMA drained ----
    __syncthreads();
    if (ci + 1 < nchunk) STAGE_K(ck + 64);   // rides PV below

    // ---- PV: O^T += V^T·P ; P B-frag via cvt_pk + shfl_xor(32) exchange ----
    // lane needs P[key=KT*16+8*hi'+j][q]. Own regs give {A1,A2}(lo-half keys)
    // and {B1,B2}(hi-half keys); partner (lane^32) supplies the other half:
    // lanes<32: w0=A1 w1=A2 w2=partnerA1 w3=partnerA2
    // lanes>=32: w0=partnerB1 w1=partnerB2 w2=B1 w3=B2
    __builtin_amdgcn_s_setprio(1);
#define PV_STEP(SCV, SUB, KT)                                                  \
    {                                                                          \
      unsigned int A1 = cvtpk(SCV[(SUB)*8+0], SCV[(SUB)*8+1]);                 \
      unsigned int A2 = cvtpk(SCV[(SUB)*8+2], SCV[(SUB)*8+3]);                 \
      unsigned int B1 = cvtpk(SCV[(SUB)*8+4], SCV[(SUB)*8+5]);                 \
      unsigned int B2 = cvtpk(SCV[(SUB)*8+6], SCV[(SUB)*8+7]);                 \
      float e0 = SCV[(SUB)*8+0] - lo2f(A1), e1 = SCV[(SUB)*8+1] - hi2f(A1);    \
      float e2 = SCV[(SUB)*8+2] - lo2f(A2), e3 = SCV[(SUB)*8+3] - hi2f(A2);    \
      float e4 = SCV[(SUB)*8+4] - lo2f(B1), e5 = SCV[(SUB)*8+5] - hi2f(B1);    \
      float e6 = SCV[(SUB)*8+6] - lo2f(B2), e7 = SCV[(SUB)*8+7] - hi2f(B2);    \
      unsigned int C1 = cvtpk(e0, e1), C2 = cvtpk(e2, e3);                     \
      unsigned int D1 = cvtpk(e4, e5), D2 = cvtpk(e6, e7);                     \
      unsigned int T1 = (unsigned int)__shfl_xor((int)(hi ? A1 : B1), 32);     \
      unsigned int T2 = (unsigned int)__shfl_xor((int)(hi ? A2 : B2), 32);     \
      unsigned int U1 = (unsigned int)__shfl_xor((int)(hi ? C1 : D1), 32);     \
      unsigned int U2 = (unsigned int)__shfl_xor((int)(hi ? C2 : D2), 32);     \
      union { unsigned int w[4]; bf16x8 v; } ph_, pl_;                         \
      ph_.w[0] = hi ? T1 : A1;  ph_.w[1] = hi ? T2 : A2;                       \
      ph_.w[2] = hi ? B1 : T1;  ph_.w[3] = hi ? B2 : T2;                       \
      pl_.w[0] = hi ? U1 : C1;  pl_.w[1] = hi ? U2 : C2;                       \
      pl_.w[2] = hi ? D1 : U1;  pl_.w[3] = hi ? D2 : U2;                       \
      const int vc = ccol[KT];                                                 \
      bf16x8 vh0 = *(const bf16x8*)&sVh[ln5 * 64 + vc];                        \
      bf16x8 vh1 = *(const bf16x8*)&sVh[(32 + ln5) * 64 + vc];                 \
      bf16x8 vh2 = *(const bf16x8*)&sVh[(64 + (ln5 & 15)) * 64 + vc];          \
      bf16x8 vl0 = *(const bf16x8*)&sVl[ln5 * 64 + vc];                        \
      bf16x8 vl1 = *(const bf16x8*)&sVl[(32 + ln5) * 64 + vc];                 \
      bf16x8 vl2 = *(const bf16x8*)&sVl[(64 + (ln5 & 15)) * 64 + vc];          \
      O0 = MFMA32(vh0, ph_.v, O0); O1 = MFMA32(vh1, ph_.v, O1);                \
      O2 = MFMA32(vh2, ph_.v, O2);                                             \
      O0 = MFMA32(vl0, ph_.v, O0); O1 = MFMA32(vl1, ph_.v, O1);                \
      O2 = MFMA32(vl2, ph_.v, O2);                                             \
      O0 = MFMA32(vh0, pl_.v, O0); O1 = MFMA32(vh1, pl_.v, O1);                \
      O2 = MFMA32(vh2, pl_.v, O2);                                             \
    }
    PV_STEP(sc0, 0, 0)
    PV_STEP(sc0, 1, 1)
    PV_STEP(sc1, 0, 2)
    PV_STEP(sc1, 1, 3)
#undef PV_STEP
    __builtin_amdgcn_s_setprio(0);

    // ---- barrier B: V reads done; K(ci+1) DMA drained ----
    __syncthreads();
    if (ci + 1 < nchunk) STAGE_V(ck + 64);   // rides next QK + softmax
  }

  // ---- epilogue: normalize (lane-local), transpose via LDS, store ----------
  const float inv = 1.0f / l_i;
  unsigned short* tr = sAll + wave * 3072;     // [32 q][96 d] shorts
#define WR(OV, DT)                                                             \
  _Pragma("unroll")                                                            \
  for (int r = 0; r < 16; r += 2) {                                            \
    if ((DT) < 2 || r < 8) {                                                   \
      const int d = (DT) * 32 + (r & 3) + 8 * (r >> 2) + 4 * hi;               \
      unsigned int w = cvtpk(OV[r] * inv, OV[r + 1] * inv);                    \
      *(unsigned int*)&tr[ln5 * 96 + d] = w;                                   \
    }                                                                          \
  }
  WR(O0, 0)
  WR(O1, 1)
  WR(O2, 2)
#undef WR
  __syncthreads();
  {
    const int qq = lane >> 1, part = lane & 1;
    const unsigned short* src = tr + qq * 96 + part * 40;
    unsigned short* dst = ohi + (size_t)(r0 + wave * 32 + qq) * HID + h * HD + part * 40;
#pragma unroll
    for (int i = 0; i < 5; ++i)
      *(u16x8*)&dst[i * 8] = *(const u16x8*)&src[i * 8];
  }
}

// ---------------- host launcher ---------------------------------------------
extern "C" void kernel_launch(void* const* d_in, const int* in_sizes, int n_in,
                              void* d_out, int out_size, void* d_ws, size_t ws_size,
                              hipStream_t stream) {
  const float* x      = (const float*)d_in[0];
  const int*   cu     = (const int*)d_in[1];
  const float* cs     = (const float*)d_in[2];
  const float* sn     = (const float*)d_in[3];
  const float* w_qkv  = (const float*)d_in[4];
  const float* b_qkv  = (const float*)d_in[5];
  const float* w_proj = (const float*)d_in[6];
  const float* b_proj = (const float*)d_in[7];
  float* out = (float*)d_out;

  char* ws = (char*)d_ws;
  float*          qf     = (float*)(ws + 0);
  float*          kf     = (float*)(ws + 20971520ULL);
  unsigned short* vthi   = (unsigned short*)(ws + 20971520ULL);
  unsigned short* vtlo   = (unsigned short*)(ws + 31457280ULL);
  float*          vf     = (float*)(ws + 41943040ULL);
  unsigned short* o_hi   = (unsigned short*)(ws + 41943040ULL);
  unsigned short* x_hi   = (unsigned short*)(ws + 62914560ULL);
  unsigned short* khi    = (unsigned short*)(ws + 62914560ULL);
  unsigned short* klo    = (unsigned short*)(ws + 73400320ULL);
  unsigned short* wqt_hi = (unsigned short*)(ws + 83886080ULL);
  unsigned short* wqt_lo = (unsigned short*)(ws + 93716480ULL);
  unsigned short* wpt_hi = (unsigned short*)(ws + 103546880ULL);
  unsigned short* wpt_lo = (unsigned short*)(ws + 106823680ULL);

  split_hi_kernel<<<5120, 256, 0, stream>>>(x, x_hi, 1310720);
  tsplit_kernel<<<dim3(120, 40), 256, 0, stream>>>(w_qkv, wqt_hi, wqt_lo, 1280, 3840);
  tsplit_kernel<<<dim3(40, 40), 256, 0, stream>>>(w_proj, wpt_hi, wpt_lo, 1280, 1280);
  gemm128_x2<<<dim3(30, 32), 256, 0, stream>>>(x_hi, wqt_hi, wqt_lo, b_qkv,
                                               qf, kf, vf, 4096, 3840, 1280);
  rope_pack_kernel<<<dim3(64, 16), 256, 0, stream>>>(qf, kf, cs, sn, khi, klo);
  vt_pack_kernel<<<dim3(64, 16), 256, 0, stream>>>(vf, vthi, vtlo);
  attn_kernel<<<1024, 128, 0, stream>>>(qf, khi, klo, vthi, vtlo, cu, o_hi);
  gemm128_x2<<<dim3(10, 32), 256, 0, stream>>>(o_hi, wpt_hi, wpt_lo, b_proj,
                                               out, nullptr, nullptr, 4096, 1280, 1280);
}